// Round 1
// baseline (318.868 us; speedup 1.0000x reference)
//
#include <hip/hip_runtime.h>
#include <cstdint>

// ---------------- types ----------------
typedef __bf16 bf16x8 __attribute__((ext_vector_type(8)));
typedef __bf16 bf16x4 __attribute__((ext_vector_type(4)));
typedef float  f32x4  __attribute__((ext_vector_type(4)));

#define N_PTS 8192
#define FDIM  64
#define NF    (N_PTS * FDIM)

__device__ __forceinline__ float ftanh(float x) {
    float e = __expf(2.f * x);
    return 1.f - 2.f / (e + 1.f);
}

// ---------------- kernel 1: per-pair encode MLP -> xe (bf16) ----------------
__global__ __launch_bounds__(256) void k_encode(
    const float* __restrict__ x,
    const float* __restrict__ w1, const float* __restrict__ b1,
    const float* __restrict__ w2, const float* __restrict__ b2,
    const float* __restrict__ w3, const float* __restrict__ b3,
    __bf16* __restrict__ xe)
{
    int idx = blockIdx.x * 256 + threadIdx.x;   // < NF
    float2 p = ((const float2*)x)[idx];
    float h1[4], h2[4];
#pragma unroll
    for (int o = 0; o < 4; o++)
        h1[o] = ftanh(p.x * w1[o] + p.y * w1[4 + o] + b1[o]);
#pragma unroll
    for (int o = 0; o < 4; o++) {
        float s = b2[o];
#pragma unroll
        for (int i = 0; i < 4; i++) s += h1[i] * w2[i * 4 + o];
        h2[o] = ftanh(s);
    }
    float s3 = b3[0];
#pragma unroll
    for (int i = 0; i < 4; i++) s3 += h2[i] * w3[i];
    xe[idx] = (__bf16)ftanh(s3);
}

// ---------------- kernel 2: D_j = sum_i exp(S[i,j])  (row sums, S symmetric) ----
// grid (128 j-tiles, 4 i-slices), 4 waves/block; wave w owns 16 j-rows.
__global__ __launch_bounds__(256) void k_pass1(
    const __bf16* __restrict__ xe, float* __restrict__ D)
{
    __shared__ __bf16 sJ[64 * 64];
    __shared__ __bf16 sI[64 * 64];
    const int tid = threadIdx.x;
    const int j0 = blockIdx.x * 64;
    const int ibase = blockIdx.y * 2048;   // N/4 per slice

#pragma unroll
    for (int k = 0; k < 2; k++) {
        int seg = tid + k * 256; int r = seg >> 3, c8 = seg & 7;
        *(uint4*)(sJ + r * 64 + c8 * 8) = *(const uint4*)(xe + (j0 + r) * 64 + c8 * 8);
    }
    __syncthreads();

    const int wave = tid >> 6, lane = tid & 63, c = lane & 15, q = lane >> 4;
    // A-frags: A[m][k] = xe[j0+16w+m][k]  (persist)
    bf16x8 a0 = *(const bf16x8*)(sJ + (16 * wave + c) * 64 + q * 8);
    bf16x8 a1 = *(const bf16x8*)(sJ + (16 * wave + c) * 64 + 32 + q * 8);

    f32x4 esum = {0.f, 0.f, 0.f, 0.f};
    for (int ic = 0; ic < 32; ic++) {
        __syncthreads();
#pragma unroll
        for (int k = 0; k < 2; k++) {
            int seg = tid + k * 256; int r = seg >> 3, c8 = seg & 7;
            *(uint4*)(sI + r * 64 + c8 * 8) =
                *(const uint4*)(xe + (ibase + ic * 64 + r) * 64 + c8 * 8);
        }
        __syncthreads();
#pragma unroll
        for (int it = 0; it < 4; it++) {
            bf16x8 b0 = *(const bf16x8*)(sI + (16 * it + c) * 64 + q * 8);
            bf16x8 b1 = *(const bf16x8*)(sI + (16 * it + c) * 64 + 32 + q * 8);
            f32x4 s = {0.f, 0.f, 0.f, 0.f};
            s = __builtin_amdgcn_mfma_f32_16x16x32_bf16(a0, b0, s, 0, 0, 0);
            s = __builtin_amdgcn_mfma_f32_16x16x32_bf16(a1, b1, s, 0, 0, 0);
            // lane holds S[j=16w+4q+r][i=16it+c]; sum exp over i
            esum.x += __expf(s.x); esum.y += __expf(s.y);
            esum.z += __expf(s.z); esum.w += __expf(s.w);
        }
    }
    // reduce across the 16 c-lanes
#pragma unroll
    for (int m = 1; m < 16; m <<= 1) {
        esum.x += __shfl_xor(esum.x, m); esum.y += __shfl_xor(esum.y, m);
        esum.z += __shfl_xor(esum.z, m); esum.w += __shfl_xor(esum.w, m);
    }
    if (c == 0) {
        atomicAdd(&D[j0 + 16 * wave + 4 * q + 0], esum.x);
        atomicAdd(&D[j0 + 16 * wave + 4 * q + 1], esum.y);
        atomicAdd(&D[j0 + 16 * wave + 4 * q + 2], esum.z);
        atomicAdd(&D[j0 + 16 * wave + 4 * q + 3], esum.w);
    }
}

// ---------------- kernel 3: uT[f][j] = bf16(xe[j][f] / D[j]) -----------------
__global__ __launch_bounds__(256) void k_build_u(
    const __bf16* __restrict__ xe, const float* __restrict__ D,
    __bf16* __restrict__ uT)
{
    __shared__ __bf16 T[64 * 72];        // [f][j_local], stride 72 (144 B)
    const int tid = threadIdx.x;
    const int j0 = blockIdx.x * 64;
    const int r = tid >> 2, cg = tid & 3;
    float invd = 1.0f / D[j0 + r];
    bf16x8 v0 = *(const bf16x8*)(xe + (j0 + r) * 64 + cg * 16);
    bf16x8 v1 = *(const bf16x8*)(xe + (j0 + r) * 64 + cg * 16 + 8);
#pragma unroll
    for (int e = 0; e < 8; e++) {
        T[(cg * 16 + e) * 72 + r]     = (__bf16)((float)v0[e] * invd);
        T[(cg * 16 + 8 + e) * 72 + r] = (__bf16)((float)v1[e] * invd);
    }
    __syncthreads();
    uint4 w0 = *(uint4*)((char*)T + r * 144 + cg * 32);
    uint4 w1 = *(uint4*)((char*)T + r * 144 + cg * 32 + 16);
    *(uint4*)(uT + r * 8192 + j0 + cg * 16)     = w0;
    *(uint4*)(uT + r * 8192 + j0 + cg * 16 + 8) = w1;
}

// ---------------- kernel 4: out = exp(S) @ u  (fused, MFMA) -------------------
// grid (64 i-tiles of 128, 8 j-slices of 1024); 4 waves; wave owns 32 i-rows.
__global__ __launch_bounds__(256) void k_pass2(
    const __bf16* __restrict__ xe, const __bf16* __restrict__ uT,
    float* __restrict__ out)
{
    __shared__ __bf16 sI[128 * 64];      // xe I-tile       16 KB
    __shared__ __bf16 sJ[64 * 64];       // xe J-chunk       8 KB
    __shared__ __bf16 sU[64 * 64];       // uT J-chunk       8 KB
    __shared__ __bf16 sP[128 * 72];      // P = exp(S), padded stride  18 KB
    const int tid = threadIdx.x;
    const int ibase = blockIdx.x * 128;
    const int jbase = blockIdx.y * 1024;

#pragma unroll
    for (int k = 0; k < 4; k++) {
        int seg = tid + k * 256; int r = seg >> 3, c8 = seg & 7;
        *(uint4*)(sI + r * 64 + c8 * 8) = *(const uint4*)(xe + (ibase + r) * 64 + c8 * 8);
    }
    __syncthreads();

    const int wave = tid >> 6, lane = tid & 63, c = lane & 15, q = lane >> 4;
    // B-frags for S^T: B[k][n] = xe_I[32w+16isub+n][k]  (persist all chunks)
    bf16x8 bst[2][2];
#pragma unroll
    for (int isub = 0; isub < 2; isub++)
#pragma unroll
        for (int kc = 0; kc < 2; kc++)
            bst[isub][kc] = *(const bf16x8*)(sI + (32 * wave + 16 * isub + c) * 64 + kc * 32 + q * 8);

    f32x4 o[2][4];
#pragma unroll
    for (int a = 0; a < 2; a++)
#pragma unroll
        for (int b = 0; b < 4; b++) o[a][b] = (f32x4){0.f, 0.f, 0.f, 0.f};

    for (int jc = 0; jc < 16; jc++) {
        const int j0 = jbase + jc * 64;
        __syncthreads();
#pragma unroll
        for (int k = 0; k < 2; k++) {
            int seg = tid + k * 256; int r = seg >> 3, c8 = seg & 7;
            *(uint4*)(sJ + r * 64 + c8 * 8) = *(const uint4*)(xe + (j0 + r) * 64 + c8 * 8);
            *(uint4*)(sU + r * 64 + c8 * 8) = *(const uint4*)(uT + r * 8192 + j0 + c8 * 8);
        }
        __syncthreads();

        // S^T tiles: A[m][k] = xe_J[16jt+m][k]; D[4q+r][c] = S[i=32w+16isub+c][j=16jt+4q+r]
#pragma unroll
        for (int jt = 0; jt < 4; jt++) {
            bf16x8 a0 = *(const bf16x8*)(sJ + (16 * jt + c) * 64 + q * 8);
            bf16x8 a1 = *(const bf16x8*)(sJ + (16 * jt + c) * 64 + 32 + q * 8);
#pragma unroll
            for (int isub = 0; isub < 2; isub++) {
                f32x4 s = {0.f, 0.f, 0.f, 0.f};
                s = __builtin_amdgcn_mfma_f32_16x16x32_bf16(a0, bst[isub][0], s, 0, 0, 0);
                s = __builtin_amdgcn_mfma_f32_16x16x32_bf16(a1, bst[isub][1], s, 0, 0, 0);
                bf16x4 pv;
                pv[0] = (__bf16)__expf(s[0]); pv[1] = (__bf16)__expf(s[1]);
                pv[2] = (__bf16)__expf(s[2]); pv[3] = (__bf16)__expf(s[3]);
                // P[i][j] row-major: 4 consecutive j per lane -> single b64 write
                *(bf16x4*)(sP + (32 * wave + 16 * isub + c) * 72 + 16 * jt + 4 * q) = pv;
            }
        }
        // wave-private P region: no barrier needed (compiler inserts lgkm waits)
#pragma unroll
        for (int kc = 0; kc < 2; kc++) {
            bf16x8 ap0 = *(const bf16x8*)(sP + (32 * wave + c) * 72 + kc * 32 + q * 8);
            bf16x8 ap1 = *(const bf16x8*)(sP + (32 * wave + 16 + c) * 72 + kc * 32 + q * 8);
#pragma unroll
            for (int ft = 0; ft < 4; ft++) {
                bf16x8 bu = *(const bf16x8*)(sU + (16 * ft + c) * 64 + kc * 32 + q * 8);
                o[0][ft] = __builtin_amdgcn_mfma_f32_16x16x32_bf16(ap0, bu, o[0][ft], 0, 0, 0);
                o[1][ft] = __builtin_amdgcn_mfma_f32_16x16x32_bf16(ap1, bu, o[1][ft], 0, 0, 0);
            }
        }
    }
#pragma unroll
    for (int isub = 0; isub < 2; isub++)
#pragma unroll
        for (int ft = 0; ft < 4; ft++)
#pragma unroll
            for (int r = 0; r < 4; r++)
                atomicAdd(&out[(ibase + 32 * wave + 16 * isub + 4 * q + r) * 64 + 16 * ft + c],
                          o[isub][ft][r]);
}

// ---------------- kernel 5: reduce out -> sq-sum & feature sums ---------------
__global__ __launch_bounds__(256) void k_combine(
    const float* __restrict__ out, float* __restrict__ accum)
{
    int idx = blockIdx.x * 256 + threadIdx.x;
    float o = out[idx];
    __shared__ float sv[256];
    sv[threadIdx.x] = o;
    __syncthreads();
    if (threadIdx.x < 64) {
        float t = sv[threadIdx.x] + sv[threadIdx.x + 64] +
                  sv[threadIdx.x + 128] + sv[threadIdx.x + 192];
        atomicAdd(&accum[1 + threadIdx.x], t);
    }
    float sq = o * o;
#pragma unroll
    for (int m = 32; m; m >>= 1) sq += __shfl_xor(sq, m);
    if ((threadIdx.x & 63) == 0) atomicAdd(&accum[0], sq);
}

// ---------------- kernel 6: m -> alpha, beta ---------------------------------
__global__ void k_final(
    const float* __restrict__ accum,
    const float* __restrict__ wa1, const float* __restrict__ ba1,
    const float* __restrict__ wa2, const float* __restrict__ ba2,
    const float* __restrict__ wb1, const float* __restrict__ bb1,
    const float* __restrict__ wb2, const float* __restrict__ bb2,
    float* __restrict__ out_tail)
{
    if (threadIdx.x != 0 || blockIdx.x != 0) return;
    float sq = accum[0];
    float ss = 0.f;
    for (int f = 0; f < 64; f++) { float v = accum[1 + f]; ss += v * v; }
    const float invN = 1.f / 8192.f;
    float m = 2.f * invN * sq - 2.f * invN * invN * ss;
    float h0 = tanhf(m * wa1[0] + ba1[0]);
    float h1 = tanhf(m * wa1[1] + ba1[1]);
    float a  = tanhf(h0 * wa2[0] + h1 * wa2[1] + ba2[0]);
    float g0 = tanhf(m * wb1[0] + bb1[0]);
    float g1 = tanhf(m * wb1[1] + bb1[1]);
    float b  = tanhf(g0 * wb2[0] + g1 * wb2[1] + bb2[0]);
    out_tail[0] = __expf(3.f * a);
    out_tail[1] = __expf(-3.f * b);
}

// ---------------- launcher ----------------------------------------------------
extern "C" void kernel_launch(void* const* d_in, const int* in_sizes, int n_in,
                              void* d_out, int out_size, void* d_ws, size_t ws_size,
                              hipStream_t stream)
{
    const float* x     = (const float*)d_in[0];
    const float* w_in1 = (const float*)d_in[1];
    const float* b_in1 = (const float*)d_in[2];
    const float* w_in2 = (const float*)d_in[3];
    const float* b_in2 = (const float*)d_in[4];
    const float* w_in3 = (const float*)d_in[5];
    const float* b_in3 = (const float*)d_in[6];
    const float* w_a1  = (const float*)d_in[7];
    const float* b_a1  = (const float*)d_in[8];
    const float* w_a2  = (const float*)d_in[9];
    const float* b_a2  = (const float*)d_in[10];
    const float* w_b1  = (const float*)d_in[11];
    const float* b_b1  = (const float*)d_in[12];
    const float* w_b2  = (const float*)d_in[13];
    const float* b_b2  = (const float*)d_in[14];

    float* out = (float*)d_out;
    char*  ws  = (char*)d_ws;
    __bf16* xe = (__bf16*)ws;                          // 1 MB
    __bf16* uT = (__bf16*)(ws + (1 << 20));            // 1 MB
    float*  D  = (float*)(ws + (2 << 20));             // 32 KB
    float*  accum = (float*)(ws + (2 << 20) + 32768);  // 65 floats

    hipMemsetAsync(D, 0, N_PTS * sizeof(float), stream);
    hipMemsetAsync(accum, 0, 65 * sizeof(float), stream);
    hipMemsetAsync(out, 0, (size_t)out_size * sizeof(float), stream);

    k_encode<<<NF / 256, 256, 0, stream>>>(x, w_in1, b_in1, w_in2, b_in2, w_in3, b_in3, xe);
    k_pass1<<<dim3(128, 4), 256, 0, stream>>>(xe, D);
    k_build_u<<<128, 256, 0, stream>>>(xe, D, uT);
    k_pass2<<<dim3(64, 8), 256, 0, stream>>>(xe, uT, out);
    k_combine<<<NF / 256, 256, 0, stream>>>(out, accum);
    k_final<<<1, 64, 0, stream>>>(accum, w_a1, b_a1, w_a2, b_a2,
                                  w_b1, b_b1, w_b2, b_b2, out + NF);
}

// Round 2
// 171.632 us; speedup vs baseline: 1.8579x; 1.8579x over previous
//
#include <hip/hip_runtime.h>
#include <cstdint>

// ---------------- types ----------------
typedef __bf16 bf16x8 __attribute__((ext_vector_type(8)));
typedef __bf16 bf16x4 __attribute__((ext_vector_type(4)));
typedef float  f32x4  __attribute__((ext_vector_type(4)));

#define N_PTS 8192
#define FDIM  64
#define NF    (N_PTS * FDIM)

__device__ __forceinline__ float ftanh(float x) {
    float e = __expf(2.f * x);
    return 1.f - 2.f / (e + 1.f);
}

// ---------------- kernel 1: per-pair encode MLP -> xe (bf16) ----------------
__global__ __launch_bounds__(256) void k_encode(
    const float* __restrict__ x,
    const float* __restrict__ w1, const float* __restrict__ b1,
    const float* __restrict__ w2, const float* __restrict__ b2,
    const float* __restrict__ w3, const float* __restrict__ b3,
    __bf16* __restrict__ xe)
{
    int idx = blockIdx.x * 256 + threadIdx.x;   // < NF
    float2 p = ((const float2*)x)[idx];
    float h1[4], h2[4];
#pragma unroll
    for (int o = 0; o < 4; o++)
        h1[o] = ftanh(p.x * w1[o] + p.y * w1[4 + o] + b1[o]);
#pragma unroll
    for (int o = 0; o < 4; o++) {
        float s = b2[o];
#pragma unroll
        for (int i = 0; i < 4; i++) s += h1[i] * w2[i * 4 + o];
        h2[o] = ftanh(s);
    }
    float s3 = b3[0];
#pragma unroll
    for (int i = 0; i < 4; i++) s3 += h2[i] * w3[i];
    xe[idx] = (__bf16)ftanh(s3);
}

// ---------------- kernel 2: D_j = sum_i exp(S[i,j])  (row sums, S symmetric) ----
// grid (128 j-tiles, 4 i-slices), 4 waves/block; wave w owns 16 j-rows.
__global__ __launch_bounds__(256) void k_pass1(
    const __bf16* __restrict__ xe, float* __restrict__ D)
{
    __shared__ __bf16 sJ[64 * 64];
    __shared__ __bf16 sI[64 * 64];
    const int tid = threadIdx.x;
    const int j0 = blockIdx.x * 64;
    const int ibase = blockIdx.y * 2048;   // N/4 per slice

#pragma unroll
    for (int k = 0; k < 2; k++) {
        int seg = tid + k * 256; int r = seg >> 3, c8 = seg & 7;
        *(uint4*)(sJ + r * 64 + c8 * 8) = *(const uint4*)(xe + (j0 + r) * 64 + c8 * 8);
    }
    __syncthreads();

    const int wave = tid >> 6, lane = tid & 63, c = lane & 15, q = lane >> 4;
    // A-frags: A[m][k] = xe[j0+16w+m][k]  (persist)
    bf16x8 a0 = *(const bf16x8*)(sJ + (16 * wave + c) * 64 + q * 8);
    bf16x8 a1 = *(const bf16x8*)(sJ + (16 * wave + c) * 64 + 32 + q * 8);

    f32x4 esum = {0.f, 0.f, 0.f, 0.f};
    for (int ic = 0; ic < 32; ic++) {
        __syncthreads();
#pragma unroll
        for (int k = 0; k < 2; k++) {
            int seg = tid + k * 256; int r = seg >> 3, c8 = seg & 7;
            *(uint4*)(sI + r * 64 + c8 * 8) =
                *(const uint4*)(xe + (ibase + ic * 64 + r) * 64 + c8 * 8);
        }
        __syncthreads();
#pragma unroll
        for (int it = 0; it < 4; it++) {
            bf16x8 b0 = *(const bf16x8*)(sI + (16 * it + c) * 64 + q * 8);
            bf16x8 b1 = *(const bf16x8*)(sI + (16 * it + c) * 64 + 32 + q * 8);
            f32x4 s = {0.f, 0.f, 0.f, 0.f};
            s = __builtin_amdgcn_mfma_f32_16x16x32_bf16(a0, b0, s, 0, 0, 0);
            s = __builtin_amdgcn_mfma_f32_16x16x32_bf16(a1, b1, s, 0, 0, 0);
            // lane holds S[j=16w+4q+r][i=16it+c]; sum exp over i
            esum.x += __expf(s.x); esum.y += __expf(s.y);
            esum.z += __expf(s.z); esum.w += __expf(s.w);
        }
    }
    // reduce across the 16 c-lanes
#pragma unroll
    for (int m = 1; m < 16; m <<= 1) {
        esum.x += __shfl_xor(esum.x, m); esum.y += __shfl_xor(esum.y, m);
        esum.z += __shfl_xor(esum.z, m); esum.w += __shfl_xor(esum.w, m);
    }
    if (c == 0) {
        atomicAdd(&D[j0 + 16 * wave + 4 * q + 0], esum.x);
        atomicAdd(&D[j0 + 16 * wave + 4 * q + 1], esum.y);
        atomicAdd(&D[j0 + 16 * wave + 4 * q + 2], esum.z);
        atomicAdd(&D[j0 + 16 * wave + 4 * q + 3], esum.w);
    }
}

// ---------------- kernel 3: uT[f][j] = bf16(xe[j][f] / D[j]) -----------------
__global__ __launch_bounds__(256) void k_build_u(
    const __bf16* __restrict__ xe, const float* __restrict__ D,
    __bf16* __restrict__ uT)
{
    __shared__ __bf16 T[64 * 72];        // [f][j_local], stride 72 (144 B)
    const int tid = threadIdx.x;
    const int j0 = blockIdx.x * 64;
    const int r = tid >> 2, cg = tid & 3;
    float invd = 1.0f / D[j0 + r];
    bf16x8 v0 = *(const bf16x8*)(xe + (j0 + r) * 64 + cg * 16);
    bf16x8 v1 = *(const bf16x8*)(xe + (j0 + r) * 64 + cg * 16 + 8);
#pragma unroll
    for (int e = 0; e < 8; e++) {
        T[(cg * 16 + e) * 72 + r]     = (__bf16)((float)v0[e] * invd);
        T[(cg * 16 + 8 + e) * 72 + r] = (__bf16)((float)v1[e] * invd);
    }
    __syncthreads();
    uint4 w0 = *(uint4*)((char*)T + r * 144 + cg * 32);
    uint4 w1 = *(uint4*)((char*)T + r * 144 + cg * 32 + 16);
    *(uint4*)(uT + r * 8192 + j0 + cg * 16)     = w0;
    *(uint4*)(uT + r * 8192 + j0 + cg * 16 + 8) = w1;
}

// ---------------- kernel 4: out = exp(S) @ u  (fused, MFMA) -------------------
// grid (64 i-tiles of 128, 8 j-slices of 1024); 4 waves; wave owns 32 i-rows.
__global__ __launch_bounds__(256) void k_pass2(
    const __bf16* __restrict__ xe, const __bf16* __restrict__ uT,
    float* __restrict__ out)
{
    __shared__ __bf16 sI[128 * 64];      // xe I-tile       16 KB
    __shared__ __bf16 sJ[64 * 64];       // xe J-chunk       8 KB
    __shared__ __bf16 sU[64 * 64];       // uT J-chunk       8 KB
    __shared__ __bf16 sP[128 * 72];      // P = exp(S), padded stride  18 KB
    const int tid = threadIdx.x;
    const int ibase = blockIdx.x * 128;
    const int jbase = blockIdx.y * 1024;

#pragma unroll
    for (int k = 0; k < 4; k++) {
        int seg = tid + k * 256; int r = seg >> 3, c8 = seg & 7;
        *(uint4*)(sI + r * 64 + c8 * 8) = *(const uint4*)(xe + (ibase + r) * 64 + c8 * 8);
    }
    __syncthreads();

    const int wave = tid >> 6, lane = tid & 63, c = lane & 15, q = lane >> 4;
    // B-frags for S^T: B[k][n] = xe_I[32w+16isub+n][k]  (persist all chunks)
    bf16x8 bst[2][2];
#pragma unroll
    for (int isub = 0; isub < 2; isub++)
#pragma unroll
        for (int kc = 0; kc < 2; kc++)
            bst[isub][kc] = *(const bf16x8*)(sI + (32 * wave + 16 * isub + c) * 64 + kc * 32 + q * 8);

    f32x4 o[2][4];
#pragma unroll
    for (int a = 0; a < 2; a++)
#pragma unroll
        for (int b = 0; b < 4; b++) o[a][b] = (f32x4){0.f, 0.f, 0.f, 0.f};

    for (int jc = 0; jc < 16; jc++) {
        const int j0 = jbase + jc * 64;
        __syncthreads();
#pragma unroll
        for (int k = 0; k < 2; k++) {
            int seg = tid + k * 256; int r = seg >> 3, c8 = seg & 7;
            *(uint4*)(sJ + r * 64 + c8 * 8) = *(const uint4*)(xe + (j0 + r) * 64 + c8 * 8);
            *(uint4*)(sU + r * 64 + c8 * 8) = *(const uint4*)(uT + r * 8192 + j0 + c8 * 8);
        }
        __syncthreads();

        // S^T tiles: A[m][k] = xe_J[16jt+m][k]; D[4q+r][c] = S[i=32w+16isub+c][j=16jt+4q+r]
#pragma unroll
        for (int jt = 0; jt < 4; jt++) {
            bf16x8 a0 = *(const bf16x8*)(sJ + (16 * jt + c) * 64 + q * 8);
            bf16x8 a1 = *(const bf16x8*)(sJ + (16 * jt + c) * 64 + 32 + q * 8);
#pragma unroll
            for (int isub = 0; isub < 2; isub++) {
                f32x4 s = {0.f, 0.f, 0.f, 0.f};
                s = __builtin_amdgcn_mfma_f32_16x16x32_bf16(a0, bst[isub][0], s, 0, 0, 0);
                s = __builtin_amdgcn_mfma_f32_16x16x32_bf16(a1, bst[isub][1], s, 0, 0, 0);
                bf16x4 pv;
                pv[0] = (__bf16)__expf(s[0]); pv[1] = (__bf16)__expf(s[1]);
                pv[2] = (__bf16)__expf(s[2]); pv[3] = (__bf16)__expf(s[3]);
                // P[i][j] row-major: 4 consecutive j per lane -> single b64 write
                *(bf16x4*)(sP + (32 * wave + 16 * isub + c) * 72 + 16 * jt + 4 * q) = pv;
            }
        }
        // wave-private P region: no barrier needed (compiler inserts lgkm waits)
#pragma unroll
        for (int kc = 0; kc < 2; kc++) {
            bf16x8 ap0 = *(const bf16x8*)(sP + (32 * wave + c) * 72 + kc * 32 + q * 8);
            bf16x8 ap1 = *(const bf16x8*)(sP + (32 * wave + 16 + c) * 72 + kc * 32 + q * 8);
#pragma unroll
            for (int ft = 0; ft < 4; ft++) {
                bf16x8 bu = *(const bf16x8*)(sU + (16 * ft + c) * 64 + kc * 32 + q * 8);
                o[0][ft] = __builtin_amdgcn_mfma_f32_16x16x32_bf16(ap0, bu, o[0][ft], 0, 0, 0);
                o[1][ft] = __builtin_amdgcn_mfma_f32_16x16x32_bf16(ap1, bu, o[1][ft], 0, 0, 0);
            }
        }
    }
#pragma unroll
    for (int isub = 0; isub < 2; isub++)
#pragma unroll
        for (int ft = 0; ft < 4; ft++)
#pragma unroll
            for (int r = 0; r < 4; r++)
                atomicAdd(&out[(ibase + 32 * wave + 16 * isub + 4 * q + r) * 64 + 16 * ft + c],
                          o[isub][ft][r]);
}

// ---------------- kernel 5: no-atomic two-stage reduction ---------------------
// 256 blocks; thread handles 8 elements at stride 65536 (stride%64==0 so each
// thread owns a single fixed feature column). Block writes 64 col-partials +
// 1 sq-partial to workspace. No atomics anywhere.
__global__ __launch_bounds__(256) void k_combine(
    const float* __restrict__ out, float* __restrict__ colp,
    float* __restrict__ sqp)
{
    const int tid = threadIdx.x;
    const int base = blockIdx.x * 256 + tid;
    float col = 0.f, sq = 0.f;
#pragma unroll
    for (int k = 0; k < 8; k++) {
        float o = out[base + k * 65536];
        col += o; sq += o * o;
    }
    __shared__ float sv[256];
    __shared__ float sw[4];
    sv[tid] = col;
#pragma unroll
    for (int m = 32; m; m >>= 1) sq += __shfl_xor(sq, m);
    if ((tid & 63) == 0) sw[tid >> 6] = sq;
    __syncthreads();
    if (tid < 64) {
        float t = sv[tid] + sv[tid + 64] + sv[tid + 128] + sv[tid + 192];
        colp[blockIdx.x * 64 + tid] = t;
    }
    if (tid == 0) sqp[blockIdx.x] = sw[0] + sw[1] + sw[2] + sw[3];
}

// ---------------- kernel 6: reduce partials, m -> alpha, beta -----------------
__global__ void k_final(
    const float* __restrict__ colp, const float* __restrict__ sqp,
    const float* __restrict__ wa1, const float* __restrict__ ba1,
    const float* __restrict__ wa2, const float* __restrict__ ba2,
    const float* __restrict__ wb1, const float* __restrict__ bb1,
    const float* __restrict__ wb2, const float* __restrict__ bb2,
    float* __restrict__ out_tail)
{
    const int f = threadIdx.x;   // 64 threads, 1 block
    float colsum = 0.f;
    for (int b = 0; b < 256; b++) colsum += colp[b * 64 + f];
    float ss = colsum * colsum;
#pragma unroll
    for (int m = 32; m; m >>= 1) ss += __shfl_xor(ss, m);
    float sq = 0.f;
#pragma unroll
    for (int k = 0; k < 4; k++) sq += sqp[f + 64 * k];
#pragma unroll
    for (int m = 32; m; m >>= 1) sq += __shfl_xor(sq, m);
    if (f == 0) {
        const float invN = 1.f / 8192.f;
        float m = 2.f * invN * sq - 2.f * invN * invN * ss;
        float h0 = tanhf(m * wa1[0] + ba1[0]);
        float h1 = tanhf(m * wa1[1] + ba1[1]);
        float a  = tanhf(h0 * wa2[0] + h1 * wa2[1] + ba2[0]);
        float g0 = tanhf(m * wb1[0] + bb1[0]);
        float g1 = tanhf(m * wb1[1] + bb1[1]);
        float b  = tanhf(g0 * wb2[0] + g1 * wb2[1] + bb2[0]);
        out_tail[0] = __expf(3.f * a);
        out_tail[1] = __expf(-3.f * b);
    }
}

// ---------------- launcher ----------------------------------------------------
extern "C" void kernel_launch(void* const* d_in, const int* in_sizes, int n_in,
                              void* d_out, int out_size, void* d_ws, size_t ws_size,
                              hipStream_t stream)
{
    const float* x     = (const float*)d_in[0];
    const float* w_in1 = (const float*)d_in[1];
    const float* b_in1 = (const float*)d_in[2];
    const float* w_in2 = (const float*)d_in[3];
    const float* b_in2 = (const float*)d_in[4];
    const float* w_in3 = (const float*)d_in[5];
    const float* b_in3 = (const float*)d_in[6];
    const float* w_a1  = (const float*)d_in[7];
    const float* b_a1  = (const float*)d_in[8];
    const float* w_a2  = (const float*)d_in[9];
    const float* b_a2  = (const float*)d_in[10];
    const float* w_b1  = (const float*)d_in[11];
    const float* b_b1  = (const float*)d_in[12];
    const float* w_b2  = (const float*)d_in[13];
    const float* b_b2  = (const float*)d_in[14];

    float* out = (float*)d_out;
    char*  ws  = (char*)d_ws;
    __bf16* xe = (__bf16*)ws;                          // 1 MB
    __bf16* uT = (__bf16*)(ws + (1 << 20));            // 1 MB
    float*  D  = (float*)(ws + (2 << 20));             // 32 KB
    float*  colp = (float*)(ws + (2 << 20) + 32768);   // 64 KB
    float*  sqp  = (float*)(ws + (2 << 20) + 32768 + 65536); // 1 KB

    hipMemsetAsync(D, 0, N_PTS * sizeof(float), stream);
    hipMemsetAsync(out, 0, (size_t)out_size * sizeof(float), stream);

    k_encode<<<NF / 256, 256, 0, stream>>>(x, w_in1, b_in1, w_in2, b_in2, w_in3, b_in3, xe);
    k_pass1<<<dim3(128, 4), 256, 0, stream>>>(xe, D);
    k_build_u<<<128, 256, 0, stream>>>(xe, D, uT);
    k_pass2<<<dim3(64, 8), 256, 0, stream>>>(xe, uT, out);
    k_combine<<<NF / 256 / 8, 256, 0, stream>>>(out, colp, sqp);
    k_final<<<1, 64, 0, stream>>>(colp, sqp, w_a1, b_a1, w_a2, b_a2,
                                  w_b1, b_b1, w_b2, b_b2, out + NF);
}

// Round 3
// 159.302 us; speedup vs baseline: 2.0017x; 1.0774x over previous
//
#include <hip/hip_runtime.h>
#include <cstdint>

// ---------------- types ----------------
typedef __bf16 bf16x8 __attribute__((ext_vector_type(8)));
typedef __bf16 bf16x4 __attribute__((ext_vector_type(4)));
typedef float  f32x4  __attribute__((ext_vector_type(4)));

#define N_PTS 8192
#define FDIM  64
#define NF    (N_PTS * FDIM)

__device__ __forceinline__ float ftanh(float x) {
    float e = __expf(2.f * x);
    return 1.f - 2.f / (e + 1.f);
}

// ---------------- kernel 1: per-pair encode MLP -> xe (bf16) ----------------
__global__ __launch_bounds__(256) void k_encode(
    const float* __restrict__ x,
    const float* __restrict__ w1, const float* __restrict__ b1,
    const float* __restrict__ w2, const float* __restrict__ b2,
    const float* __restrict__ w3, const float* __restrict__ b3,
    __bf16* __restrict__ xe)
{
    int idx = blockIdx.x * 256 + threadIdx.x;   // < NF
    float2 p = ((const float2*)x)[idx];
    float h1[4], h2[4];
#pragma unroll
    for (int o = 0; o < 4; o++)
        h1[o] = ftanh(p.x * w1[o] + p.y * w1[4 + o] + b1[o]);
#pragma unroll
    for (int o = 0; o < 4; o++) {
        float s = b2[o];
#pragma unroll
        for (int i = 0; i < 4; i++) s += h1[i] * w2[i * 4 + o];
        h2[o] = ftanh(s);
    }
    float s3 = b3[0];
#pragma unroll
    for (int i = 0; i < 4; i++) s3 += h2[i] * w3[i];
    xe[idx] = (__bf16)ftanh(s3);
}

// ---------------- kernel 2: D partials -----------------------------------------
// Flipped decomposition: block owns 64 j (B-frags persist in REGISTERS, loaded
// once from global); i-rows streamed through LDS, split across waves so each
// i-row is LDS-read exactly once. grid (128 j-tiles, 8 i-slices of 1024).
// Per-wave partial D written to Dp[slice*4+wave] -> 32 partial slices.
__global__ __launch_bounds__(256) void k_pass1(
    const __bf16* __restrict__ xe, float* __restrict__ Dp)
{
    __shared__ __bf16 sI[128 * 72];            // padded stride 72: conflict-free
    const int tid = threadIdx.x;
    const int j0 = blockIdx.x * 64;
    const int ibase = blockIdx.y * 1024;
    const int wave = tid >> 6, lane = tid & 63, c = lane & 15, q = lane >> 4;

    // persist B-frags: B[k][n=c] = xe[j0+16jt+c][kc*32+q*8+e]
    bf16x8 Bf[4][2];
#pragma unroll
    for (int jt = 0; jt < 4; jt++)
#pragma unroll
        for (int kc = 0; kc < 2; kc++)
            Bf[jt][kc] = *(const bf16x8*)(xe + (j0 + 16 * jt + c) * 64 + kc * 32 + q * 8);

    float es[4] = {0.f, 0.f, 0.f, 0.f};
    for (int ic = 0; ic < 8; ic++) {
        __syncthreads();
#pragma unroll
        for (int k = 0; k < 4; k++) {
            int seg = tid + k * 256; int r = seg >> 3, c8 = seg & 7;
            *(uint4*)(sI + r * 72 + c8 * 8) =
                *(const uint4*)(xe + (ibase + ic * 128 + r) * 64 + c8 * 8);
        }
        __syncthreads();
#pragma unroll
        for (int g = 0; g < 2; g++) {
            // A-frags: this wave's own 16 i-rows (no cross-wave amplification)
            bf16x8 a0 = *(const bf16x8*)(sI + (32 * wave + 16 * g + c) * 72 + q * 8);
            bf16x8 a1 = *(const bf16x8*)(sI + (32 * wave + 16 * g + c) * 72 + 32 + q * 8);
#pragma unroll
            for (int jt = 0; jt < 4; jt++) {
                f32x4 s = {0.f, 0.f, 0.f, 0.f};
                s = __builtin_amdgcn_mfma_f32_16x16x32_bf16(a0, Bf[jt][0], s, 0, 0, 0);
                s = __builtin_amdgcn_mfma_f32_16x16x32_bf16(a1, Bf[jt][1], s, 0, 0, 0);
                // lane holds S[i=...+4q+r][j=j0+16jt+c]; sum exp over i rows
                es[jt] += __expf(s.x) + __expf(s.y) + __expf(s.z) + __expf(s.w);
            }
        }
    }
    // reduce over q (i-rows spread across lane groups of 16)
#pragma unroll
    for (int jt = 0; jt < 4; jt++) {
        es[jt] += __shfl_xor(es[jt], 16);
        es[jt] += __shfl_xor(es[jt], 32);
    }
    if (q == 0) {
        float* d = Dp + (blockIdx.y * 4 + wave) * N_PTS + j0;
#pragma unroll
        for (int jt = 0; jt < 4; jt++) d[16 * jt + c] = es[jt];
    }
}

// ---------------- kernel 3: uT[f][j] = bf16(xe[j][f] / sum(Dp[:,j])) ----------
__global__ __launch_bounds__(256) void k_build_u(
    const __bf16* __restrict__ xe, const float* __restrict__ Dp,
    __bf16* __restrict__ uT)
{
    __shared__ __bf16 T[64 * 72];        // [f][j_local], stride 72
    const int tid = threadIdx.x;
    const int j0 = blockIdx.x * 64;
    const int r = tid >> 2, cg = tid & 3;
    float dsum = 0.f;
#pragma unroll
    for (int s = 0; s < 32; s++) dsum += Dp[s * N_PTS + j0 + r];
    float invd = 1.0f / dsum;
    bf16x8 v0 = *(const bf16x8*)(xe + (j0 + r) * 64 + cg * 16);
    bf16x8 v1 = *(const bf16x8*)(xe + (j0 + r) * 64 + cg * 16 + 8);
#pragma unroll
    for (int e = 0; e < 8; e++) {
        T[(cg * 16 + e) * 72 + r]     = (__bf16)((float)v0[e] * invd);
        T[(cg * 16 + 8 + e) * 72 + r] = (__bf16)((float)v1[e] * invd);
    }
    __syncthreads();
    uint4 w0 = *(uint4*)((char*)T + r * 144 + cg * 32);
    uint4 w1 = *(uint4*)((char*)T + r * 144 + cg * 32 + 16);
    *(uint4*)(uT + r * 8192 + j0 + cg * 16)     = w0;
    *(uint4*)(uT + r * 8192 + j0 + cg * 16 + 8) = w1;
}

// ---------------- kernel 4: outp[slice] = exp(S_slice) @ u  (MFMA) ------------
// grid (64 i-tiles of 128, 16 j-slices of 512); 4 waves; wave owns 32 i-rows.
// No sI buffer (B-frags direct from global); all tiles padded to stride 72;
// plain stores to per-slice partials (no atomics).
__global__ __launch_bounds__(256) void k_pass2(
    const __bf16* __restrict__ xe, const __bf16* __restrict__ uT,
    float* __restrict__ outp)
{
    __shared__ __bf16 sJ[64 * 72];       //  9.2 KB
    __shared__ __bf16 sU[64 * 72];       //  9.2 KB
    __shared__ __bf16 sP[128 * 72];      // 18.4 KB   -> 36.9 KB total, 4 blk/CU
    const int tid = threadIdx.x;
    const int ibase = blockIdx.x * 128;
    const int jbase = blockIdx.y * 512;
    const int wave = tid >> 6, lane = tid & 63, c = lane & 15, q = lane >> 4;

    // B-frags for S^T direct from global: B[k][n] = xe_I[32w+16isub+n][k]
    bf16x8 bst[2][2];
#pragma unroll
    for (int isub = 0; isub < 2; isub++)
#pragma unroll
        for (int kc = 0; kc < 2; kc++)
            bst[isub][kc] = *(const bf16x8*)(xe + (ibase + 32 * wave + 16 * isub + c) * 64 + kc * 32 + q * 8);

    f32x4 o[2][4];
#pragma unroll
    for (int a = 0; a < 2; a++)
#pragma unroll
        for (int b = 0; b < 4; b++) o[a][b] = (f32x4){0.f, 0.f, 0.f, 0.f};

    for (int jc = 0; jc < 8; jc++) {
        const int j0 = jbase + jc * 64;
        __syncthreads();
#pragma unroll
        for (int k = 0; k < 2; k++) {
            int seg = tid + k * 256; int r = seg >> 3, c8 = seg & 7;
            *(uint4*)(sJ + r * 72 + c8 * 8) = *(const uint4*)(xe + (j0 + r) * 64 + c8 * 8);
            *(uint4*)(sU + r * 72 + c8 * 8) = *(const uint4*)(uT + r * 8192 + j0 + c8 * 8);
        }
        __syncthreads();

        // S^T tiles: A[m][k] = xe_J[16jt+m][k]; lane -> S[i=32w+16isub+c][j=16jt+4q+r]
#pragma unroll
        for (int jt = 0; jt < 4; jt++) {
            bf16x8 a0 = *(const bf16x8*)(sJ + (16 * jt + c) * 72 + q * 8);
            bf16x8 a1 = *(const bf16x8*)(sJ + (16 * jt + c) * 72 + 32 + q * 8);
#pragma unroll
            for (int isub = 0; isub < 2; isub++) {
                f32x4 s = {0.f, 0.f, 0.f, 0.f};
                s = __builtin_amdgcn_mfma_f32_16x16x32_bf16(a0, bst[isub][0], s, 0, 0, 0);
                s = __builtin_amdgcn_mfma_f32_16x16x32_bf16(a1, bst[isub][1], s, 0, 0, 0);
                bf16x4 pv;
                pv[0] = (__bf16)__expf(s[0]); pv[1] = (__bf16)__expf(s[1]);
                pv[2] = (__bf16)__expf(s[2]); pv[3] = (__bf16)__expf(s[3]);
                *(bf16x4*)(sP + (32 * wave + 16 * isub + c) * 72 + 16 * jt + 4 * q) = pv;
            }
        }
        // sP rows 32w..32w+31 are wave-private: no barrier needed
#pragma unroll
        for (int kc = 0; kc < 2; kc++) {
            bf16x8 ap0 = *(const bf16x8*)(sP + (32 * wave + c) * 72 + kc * 32 + q * 8);
            bf16x8 ap1 = *(const bf16x8*)(sP + (32 * wave + 16 + c) * 72 + kc * 32 + q * 8);
#pragma unroll
            for (int ft = 0; ft < 4; ft++) {
                bf16x8 bu = *(const bf16x8*)(sU + (16 * ft + c) * 72 + kc * 32 + q * 8);
                o[0][ft] = __builtin_amdgcn_mfma_f32_16x16x32_bf16(ap0, bu, o[0][ft], 0, 0, 0);
                o[1][ft] = __builtin_amdgcn_mfma_f32_16x16x32_bf16(ap1, bu, o[1][ft], 0, 0, 0);
            }
        }
    }
    float* dst = outp + (size_t)blockIdx.y * NF;
#pragma unroll
    for (int isub = 0; isub < 2; isub++)
#pragma unroll
        for (int ft = 0; ft < 4; ft++)
#pragma unroll
            for (int r = 0; r < 4; r++)
                dst[(ibase + 32 * wave + 16 * isub + 4 * q + r) * 64 + 16 * ft + c] =
                    o[isub][ft][r];
}

// ---------------- kernel 5: sum slices -> out, col/sq partials ----------------
// 256 blocks; thread owns 8 positions at stride 65536 (stride%64==0 -> fixed
// feature column per thread). No atomics.
__global__ __launch_bounds__(256) void k_combine(
    const float* __restrict__ outp, float* __restrict__ out,
    float* __restrict__ colp, float* __restrict__ sqp)
{
    const int tid = threadIdx.x;
    const int base = blockIdx.x * 256 + tid;
    float col = 0.f, sq = 0.f;
#pragma unroll
    for (int k = 0; k < 8; k++) {
        int idx = base + k * 65536;
        float acc = 0.f;
#pragma unroll
        for (int s = 0; s < 16; s++) acc += outp[(size_t)s * NF + idx];
        out[idx] = acc;
        col += acc; sq += acc * acc;
    }
    __shared__ float sv[256];
    __shared__ float sw[4];
    sv[tid] = col;
#pragma unroll
    for (int m = 32; m; m >>= 1) sq += __shfl_xor(sq, m);
    if ((tid & 63) == 0) sw[tid >> 6] = sq;
    __syncthreads();
    if (tid < 64) {
        float t = sv[tid] + sv[tid + 64] + sv[tid + 128] + sv[tid + 192];
        colp[blockIdx.x * 64 + tid] = t;
    }
    if (tid == 0) sqp[blockIdx.x] = sw[0] + sw[1] + sw[2] + sw[3];
}

// ---------------- kernel 6: reduce partials, m -> alpha, beta -----------------
__global__ void k_final(
    const float* __restrict__ colp, const float* __restrict__ sqp,
    const float* __restrict__ wa1, const float* __restrict__ ba1,
    const float* __restrict__ wa2, const float* __restrict__ ba2,
    const float* __restrict__ wb1, const float* __restrict__ bb1,
    const float* __restrict__ wb2, const float* __restrict__ bb2,
    float* __restrict__ out_tail)
{
    const int f = threadIdx.x;   // 64 threads, 1 block
    float colsum = 0.f;
    for (int b = 0; b < 256; b++) colsum += colp[b * 64 + f];
    float ss = colsum * colsum;
#pragma unroll
    for (int m = 32; m; m >>= 1) ss += __shfl_xor(ss, m);
    float sq = 0.f;
#pragma unroll
    for (int k = 0; k < 4; k++) sq += sqp[f + 64 * k];
#pragma unroll
    for (int m = 32; m; m >>= 1) sq += __shfl_xor(sq, m);
    if (f == 0) {
        const float invN = 1.f / 8192.f;
        float m = 2.f * invN * sq - 2.f * invN * invN * ss;
        float h0 = tanhf(m * wa1[0] + ba1[0]);
        float h1 = tanhf(m * wa1[1] + ba1[1]);
        float a  = tanhf(h0 * wa2[0] + h1 * wa2[1] + ba2[0]);
        float g0 = tanhf(m * wb1[0] + bb1[0]);
        float g1 = tanhf(m * wb1[1] + bb1[1]);
        float b  = tanhf(g0 * wb2[0] + g1 * wb2[1] + bb2[0]);
        out_tail[0] = __expf(3.f * a);
        out_tail[1] = __expf(-3.f * b);
    }
}

// ---------------- launcher ----------------------------------------------------
extern "C" void kernel_launch(void* const* d_in, const int* in_sizes, int n_in,
                              void* d_out, int out_size, void* d_ws, size_t ws_size,
                              hipStream_t stream)
{
    const float* x     = (const float*)d_in[0];
    const float* w_in1 = (const float*)d_in[1];
    const float* b_in1 = (const float*)d_in[2];
    const float* w_in2 = (const float*)d_in[3];
    const float* b_in2 = (const float*)d_in[4];
    const float* w_in3 = (const float*)d_in[5];
    const float* b_in3 = (const float*)d_in[6];
    const float* w_a1  = (const float*)d_in[7];
    const float* b_a1  = (const float*)d_in[8];
    const float* w_a2  = (const float*)d_in[9];
    const float* b_a2  = (const float*)d_in[10];
    const float* w_b1  = (const float*)d_in[11];
    const float* b_b1  = (const float*)d_in[12];
    const float* w_b2  = (const float*)d_in[13];
    const float* b_b2  = (const float*)d_in[14];

    float* out = (float*)d_out;
    char*  ws  = (char*)d_ws;
    __bf16* xe  = (__bf16*)ws;                             // 1 MB
    __bf16* uT  = (__bf16*)(ws + (1 << 20));               // 1 MB
    float*  Dp  = (float*)(ws + (2 << 20));                // 32 slices x 32 KB = 1 MB
    float*  colp = (float*)(ws + (3 << 20));               // 64 KB
    float*  sqp  = (float*)(ws + (3 << 20) + (1 << 16));   // 1 KB
    float*  outp = (float*)(ws + (4 << 20));               // 16 slices x 2 MB = 32 MB

    k_encode<<<NF / 256, 256, 0, stream>>>(x, w_in1, b_in1, w_in2, b_in2, w_in3, b_in3, xe);
    k_pass1<<<dim3(128, 8), 256, 0, stream>>>(xe, Dp);
    k_build_u<<<128, 256, 0, stream>>>(xe, Dp, uT);
    k_pass2<<<dim3(64, 16), 256, 0, stream>>>(xe, uT, outp);
    k_combine<<<256, 256, 0, stream>>>(outp, out, colp, sqp);
    k_final<<<1, 64, 0, stream>>>(colp, sqp, w_a1, b_a1, w_a2, b_a2,
                                  w_b1, b_b1, w_b2, b_b2, out + NF);
}

// Round 4
// 158.088 us; speedup vs baseline: 2.0170x; 1.0077x over previous
//
#include <hip/hip_runtime.h>
#include <cstdint>

// ---------------- types ----------------
typedef __bf16 bf16x8 __attribute__((ext_vector_type(8)));
typedef __bf16 bf16x4 __attribute__((ext_vector_type(4)));
typedef float  f32x4  __attribute__((ext_vector_type(4)));

#define N_PTS 8192
#define FDIM  64
#define NF    (N_PTS * FDIM)

__device__ __forceinline__ float ftanh(float x) {
    float e = __expf(2.f * x);
    return 1.f - 2.f / (e + 1.f);
}

// ---------------- kernel 1: per-pair encode MLP -> xe (bf16) ----------------
__global__ __launch_bounds__(256) void k_encode(
    const float* __restrict__ x,
    const float* __restrict__ w1, const float* __restrict__ b1,
    const float* __restrict__ w2, const float* __restrict__ b2,
    const float* __restrict__ w3, const float* __restrict__ b3,
    __bf16* __restrict__ xe)
{
    int idx = blockIdx.x * 256 + threadIdx.x;   // < NF
    float2 p = ((const float2*)x)[idx];
    float h1[4], h2[4];
#pragma unroll
    for (int o = 0; o < 4; o++)
        h1[o] = ftanh(p.x * w1[o] + p.y * w1[4 + o] + b1[o]);
#pragma unroll
    for (int o = 0; o < 4; o++) {
        float s = b2[o];
#pragma unroll
        for (int i = 0; i < 4; i++) s += h1[i] * w2[i * 4 + o];
        h2[o] = ftanh(s);
    }
    float s3 = b3[0];
#pragma unroll
    for (int i = 0; i < 4; i++) s3 += h2[i] * w3[i];
    xe[idx] = (__bf16)ftanh(s3);
}

// ---------------- kernel 2: D partials -----------------------------------------
// Block owns 64 j (B-frags persist in registers); i-rows streamed through LDS,
// split across waves so each i-row is LDS-read exactly once.
// grid (128 j-tiles, 8 i-slices of 1024). Dp[slice*4+wave] partial slices.
__global__ __launch_bounds__(256) void k_pass1(
    const __bf16* __restrict__ xe, float* __restrict__ Dp)
{
    __shared__ __bf16 sI[128 * 72];            // padded stride 72: conflict-free
    const int tid = threadIdx.x;
    const int j0 = blockIdx.x * 64;
    const int ibase = blockIdx.y * 1024;
    const int wave = tid >> 6, lane = tid & 63, c = lane & 15, q = lane >> 4;

    bf16x8 Bf[4][2];
#pragma unroll
    for (int jt = 0; jt < 4; jt++)
#pragma unroll
        for (int kc = 0; kc < 2; kc++)
            Bf[jt][kc] = *(const bf16x8*)(xe + (j0 + 16 * jt + c) * 64 + kc * 32 + q * 8);

    float es[4] = {0.f, 0.f, 0.f, 0.f};
    for (int ic = 0; ic < 8; ic++) {
        __syncthreads();
#pragma unroll
        for (int k = 0; k < 4; k++) {
            int seg = tid + k * 256; int r = seg >> 3, c8 = seg & 7;
            *(uint4*)(sI + r * 72 + c8 * 8) =
                *(const uint4*)(xe + (ibase + ic * 128 + r) * 64 + c8 * 8);
        }
        __syncthreads();
#pragma unroll
        for (int g = 0; g < 2; g++) {
            bf16x8 a0 = *(const bf16x8*)(sI + (32 * wave + 16 * g + c) * 72 + q * 8);
            bf16x8 a1 = *(const bf16x8*)(sI + (32 * wave + 16 * g + c) * 72 + 32 + q * 8);
#pragma unroll
            for (int jt = 0; jt < 4; jt++) {
                f32x4 s = {0.f, 0.f, 0.f, 0.f};
                s = __builtin_amdgcn_mfma_f32_16x16x32_bf16(a0, Bf[jt][0], s, 0, 0, 0);
                s = __builtin_amdgcn_mfma_f32_16x16x32_bf16(a1, Bf[jt][1], s, 0, 0, 0);
                es[jt] += __expf(s.x) + __expf(s.y) + __expf(s.z) + __expf(s.w);
            }
        }
    }
#pragma unroll
    for (int jt = 0; jt < 4; jt++) {
        es[jt] += __shfl_xor(es[jt], 16);
        es[jt] += __shfl_xor(es[jt], 32);
    }
    if (q == 0) {
        float* d = Dp + (blockIdx.y * 4 + wave) * N_PTS + j0;
#pragma unroll
        for (int jt = 0; jt < 4; jt++) d[16 * jt + c] = es[jt];
    }
}

// ---------------- kernel 3: uT[f][j] = bf16(xe[j][f] / sum(Dp[:,j])) ----------
__global__ __launch_bounds__(256) void k_build_u(
    const __bf16* __restrict__ xe, const float* __restrict__ Dp,
    __bf16* __restrict__ uT)
{
    __shared__ __bf16 T[64 * 72];
    const int tid = threadIdx.x;
    const int j0 = blockIdx.x * 64;
    const int r = tid >> 2, cg = tid & 3;
    float dsum = 0.f;
#pragma unroll
    for (int s = 0; s < 32; s++) dsum += Dp[s * N_PTS + j0 + r];
    float invd = 1.0f / dsum;
    bf16x8 v0 = *(const bf16x8*)(xe + (j0 + r) * 64 + cg * 16);
    bf16x8 v1 = *(const bf16x8*)(xe + (j0 + r) * 64 + cg * 16 + 8);
#pragma unroll
    for (int e = 0; e < 8; e++) {
        T[(cg * 16 + e) * 72 + r]     = (__bf16)((float)v0[e] * invd);
        T[(cg * 16 + 8 + e) * 72 + r] = (__bf16)((float)v1[e] * invd);
    }
    __syncthreads();
    uint4 w0 = *(uint4*)((char*)T + r * 144 + cg * 32);
    uint4 w1 = *(uint4*)((char*)T + r * 144 + cg * 32 + 16);
    *(uint4*)(uT + r * 8192 + j0 + cg * 16)     = w0;
    *(uint4*)(uT + r * 8192 + j0 + cg * 16 + 8) = w1;
}

// ---------------- kernel 4: outp[slice] = exp(S_slice) @ u  (MFMA) ------------
// grid (32 i-groups of 256, 16 j-slices of 512); 4 waves. Block processes two
// sequential 128-row i-tiles (it loop) reusing sJ/sU (read ONCE per jc into
// hoisted register frags) and the wave-private sP buffer. ~200 VGPR, 2 blk/CU.
__global__ __launch_bounds__(256, 2) void k_pass2(
    const __bf16* __restrict__ xe, const __bf16* __restrict__ uT,
    float* __restrict__ outp)
{
    __shared__ __bf16 sJ[64 * 72];       //  9.2 KB
    __shared__ __bf16 sU[64 * 72];       //  9.2 KB
    __shared__ __bf16 sP[128 * 72];      // 18.4 KB -> 36.9 KB total
    const int tid = threadIdx.x;
    const int ibase = blockIdx.x * 256;
    const int jbase = blockIdx.y * 512;
    const int wave = tid >> 6, lane = tid & 63, c = lane & 15, q = lane >> 4;

    // persist B-frags for S^T (both i-tiles): B[k][n] = xe_I[...+16isub+n][k]
    bf16x8 bst[2][2][2];
#pragma unroll
    for (int it = 0; it < 2; it++)
#pragma unroll
        for (int isub = 0; isub < 2; isub++)
#pragma unroll
            for (int kc = 0; kc < 2; kc++)
                bst[it][isub][kc] = *(const bf16x8*)(
                    xe + (ibase + it * 128 + 32 * wave + 16 * isub + c) * 64 + kc * 32 + q * 8);

    f32x4 o[2][2][4];
#pragma unroll
    for (int it = 0; it < 2; it++)
#pragma unroll
        for (int g = 0; g < 2; g++)
#pragma unroll
            for (int ft = 0; ft < 4; ft++) o[it][g][ft] = (f32x4){0.f, 0.f, 0.f, 0.f};

    for (int jc = 0; jc < 8; jc++) {
        const int j0 = jbase + jc * 64;
        __syncthreads();
#pragma unroll
        for (int k = 0; k < 2; k++) {
            int seg = tid + k * 256; int r = seg >> 3, c8 = seg & 7;
            *(uint4*)(sJ + r * 72 + c8 * 8) = *(const uint4*)(xe + (j0 + r) * 64 + c8 * 8);
            *(uint4*)(sU + r * 72 + c8 * 8) = *(const uint4*)(uT + r * 8192 + j0 + c8 * 8);
        }
        __syncthreads();

        // hoist all sJ/sU fragments once per jc (amortized over both i-tiles)
        bf16x8 aJ[4][2];
#pragma unroll
        for (int jt = 0; jt < 4; jt++)
#pragma unroll
            for (int kc = 0; kc < 2; kc++)
                aJ[jt][kc] = *(const bf16x8*)(sJ + (16 * jt + c) * 72 + kc * 32 + q * 8);
        bf16x8 bu[2][4];
#pragma unroll
        for (int kc = 0; kc < 2; kc++)
#pragma unroll
            for (int ft = 0; ft < 4; ft++)
                bu[kc][ft] = *(const bf16x8*)(sU + (16 * ft + c) * 72 + kc * 32 + q * 8);

#pragma unroll
        for (int it = 0; it < 2; it++) {
            // S-phase: lane -> S[i = ibase+it*128+32w+16isub+c][j = j0+16jt+4q+r]
#pragma unroll
            for (int jt = 0; jt < 4; jt++) {
#pragma unroll
                for (int isub = 0; isub < 2; isub++) {
                    f32x4 s = {0.f, 0.f, 0.f, 0.f};
                    s = __builtin_amdgcn_mfma_f32_16x16x32_bf16(aJ[jt][0], bst[it][isub][0], s, 0, 0, 0);
                    s = __builtin_amdgcn_mfma_f32_16x16x32_bf16(aJ[jt][1], bst[it][isub][1], s, 0, 0, 0);
                    bf16x4 pv;
                    pv[0] = (__bf16)__expf(s[0]); pv[1] = (__bf16)__expf(s[1]);
                    pv[2] = (__bf16)__expf(s[2]); pv[3] = (__bf16)__expf(s[3]);
                    *(bf16x4*)(sP + (32 * wave + 16 * isub + c) * 72 + 16 * jt + 4 * q) = pv;
                }
            }
            // PV-phase: sP rows 32w..32w+31 are wave-private; compiler inserts waits
#pragma unroll
            for (int kc = 0; kc < 2; kc++) {
                bf16x8 ap0 = *(const bf16x8*)(sP + (32 * wave + c) * 72 + kc * 32 + q * 8);
                bf16x8 ap1 = *(const bf16x8*)(sP + (32 * wave + 16 + c) * 72 + kc * 32 + q * 8);
#pragma unroll
                for (int ft = 0; ft < 4; ft++) {
                    o[it][0][ft] = __builtin_amdgcn_mfma_f32_16x16x32_bf16(ap0, bu[kc][ft], o[it][0][ft], 0, 0, 0);
                    o[it][1][ft] = __builtin_amdgcn_mfma_f32_16x16x32_bf16(ap1, bu[kc][ft], o[it][1][ft], 0, 0, 0);
                }
            }
        }
    }
    float* dst = outp + (size_t)blockIdx.y * NF;
#pragma unroll
    for (int it = 0; it < 2; it++)
#pragma unroll
        for (int g = 0; g < 2; g++)
#pragma unroll
            for (int ft = 0; ft < 4; ft++)
#pragma unroll
                for (int r = 0; r < 4; r++)
                    dst[(ibase + it * 128 + 32 * wave + 16 * g + 4 * q + r) * 64 + 16 * ft + c] =
                        o[it][g][ft][r];
}

// ---------------- kernel 5: sum slices -> out, col/sq partials ----------------
__global__ __launch_bounds__(256) void k_combine(
    const float* __restrict__ outp, float* __restrict__ out,
    float* __restrict__ colp, float* __restrict__ sqp)
{
    const int tid = threadIdx.x;
    const int base = blockIdx.x * 256 + tid;
    float col = 0.f, sq = 0.f;
#pragma unroll
    for (int k = 0; k < 8; k++) {
        int idx = base + k * 65536;
        float acc = 0.f;
#pragma unroll
        for (int s = 0; s < 16; s++) acc += outp[(size_t)s * NF + idx];
        out[idx] = acc;
        col += acc; sq += acc * acc;
    }
    __shared__ float sv[256];
    __shared__ float sw[4];
    sv[tid] = col;
#pragma unroll
    for (int m = 32; m; m >>= 1) sq += __shfl_xor(sq, m);
    if ((tid & 63) == 0) sw[tid >> 6] = sq;
    __syncthreads();
    if (tid < 64) {
        float t = sv[tid] + sv[tid + 64] + sv[tid + 128] + sv[tid + 192];
        colp[blockIdx.x * 64 + tid] = t;
    }
    if (tid == 0) sqp[blockIdx.x] = sw[0] + sw[1] + sw[2] + sw[3];
}

// ---------------- kernel 6: reduce partials, m -> alpha, beta -----------------
__global__ void k_final(
    const float* __restrict__ colp, const float* __restrict__ sqp,
    const float* __restrict__ wa1, const float* __restrict__ ba1,
    const float* __restrict__ wa2, const float* __restrict__ ba2,
    const float* __restrict__ wb1, const float* __restrict__ bb1,
    const float* __restrict__ wb2, const float* __restrict__ bb2,
    float* __restrict__ out_tail)
{
    const int f = threadIdx.x;   // 64 threads, 1 block
    float colsum = 0.f;
    for (int b = 0; b < 256; b++) colsum += colp[b * 64 + f];
    float ss = colsum * colsum;
#pragma unroll
    for (int m = 32; m; m >>= 1) ss += __shfl_xor(ss, m);
    float sq = 0.f;
#pragma unroll
    for (int k = 0; k < 4; k++) sq += sqp[f + 64 * k];
#pragma unroll
    for (int m = 32; m; m >>= 1) sq += __shfl_xor(sq, m);
    if (f == 0) {
        const float invN = 1.f / 8192.f;
        float m = 2.f * invN * sq - 2.f * invN * invN * ss;
        float h0 = tanhf(m * wa1[0] + ba1[0]);
        float h1 = tanhf(m * wa1[1] + ba1[1]);
        float a  = tanhf(h0 * wa2[0] + h1 * wa2[1] + ba2[0]);
        float g0 = tanhf(m * wb1[0] + bb1[0]);
        float g1 = tanhf(m * wb1[1] + bb1[1]);
        float b  = tanhf(g0 * wb2[0] + g1 * wb2[1] + bb2[0]);
        out_tail[0] = __expf(3.f * a);
        out_tail[1] = __expf(-3.f * b);
    }
}

// ---------------- launcher ----------------------------------------------------
extern "C" void kernel_launch(void* const* d_in, const int* in_sizes, int n_in,
                              void* d_out, int out_size, void* d_ws, size_t ws_size,
                              hipStream_t stream)
{
    const float* x     = (const float*)d_in[0];
    const float* w_in1 = (const float*)d_in[1];
    const float* b_in1 = (const float*)d_in[2];
    const float* w_in2 = (const float*)d_in[3];
    const float* b_in2 = (const float*)d_in[4];
    const float* w_in3 = (const float*)d_in[5];
    const float* b_in3 = (const float*)d_in[6];
    const float* w_a1  = (const float*)d_in[7];
    const float* b_a1  = (const float*)d_in[8];
    const float* w_a2  = (const float*)d_in[9];
    const float* b_a2  = (const float*)d_in[10];
    const float* w_b1  = (const float*)d_in[11];
    const float* b_b1  = (const float*)d_in[12];
    const float* w_b2  = (const float*)d_in[13];
    const float* b_b2  = (const float*)d_in[14];

    float* out = (float*)d_out;
    char*  ws  = (char*)d_ws;
    __bf16* xe  = (__bf16*)ws;                             // 1 MB
    __bf16* uT  = (__bf16*)(ws + (1 << 20));               // 1 MB
    float*  Dp  = (float*)(ws + (2 << 20));                // 32 x 32 KB = 1 MB
    float*  colp = (float*)(ws + (3 << 20));               // 64 KB
    float*  sqp  = (float*)(ws + (3 << 20) + (1 << 16));   // 1 KB
    float*  outp = (float*)(ws + (4 << 20));               // 16 x 2 MB = 32 MB

    k_encode<<<NF / 256, 256, 0, stream>>>(x, w_in1, b_in1, w_in2, b_in2, w_in3, b_in3, xe);
    k_pass1<<<dim3(128, 8), 256, 0, stream>>>(xe, Dp);
    k_build_u<<<128, 256, 0, stream>>>(xe, Dp, uT);
    k_pass2<<<dim3(32, 16), 256, 0, stream>>>(xe, uT, outp);
    k_combine<<<256, 256, 0, stream>>>(outp, out, colp, sqp);
    k_final<<<1, 64, 0, stream>>>(colp, sqp, w_a1, b_a1, w_a2, b_a2,
                                  w_b1, b_b1, w_b2, b_b2, out + NF);
}